// Round 6
// baseline (112.493 us; speedup 1.0000x reference)
//
#include <hip/hip_runtime.h>

typedef unsigned short ushort_t;
typedef short bf16x8 __attribute__((ext_vector_type(8)));
typedef float f32x4 __attribute__((ext_vector_type(4)));

#define B_ 8
#define L_ 512
#define D_ 1024
#define H_ 16
#define M_ 4096

__device__ __forceinline__ ushort_t f2bf(float f) {
  union { float f; unsigned u; } v; v.f = f;
  unsigned r = v.u + 0x7FFFu + ((v.u >> 16) & 1u);
  return (ushort_t)(r >> 16);
}

// global -> LDS direct (16B per lane, dest = wave-uniform base + lane*16)
__device__ __forceinline__ void gl_lds16(const ushort_t* g, ushort_t* s) {
  __builtin_amdgcn_global_load_lds((const __attribute__((address_space(1))) void*)(g),
                                   (__attribute__((address_space(3))) void*)(s), 16, 0, 0);
}

// ---------------- fused preamble: LN (blocks 0..4095), cos/sin table (4096..4159),
// ---------------- weight transpose+bf16 (4160..8255) ----------------
__global__ __launch_bounds__(256) void prep_kernel(const float* __restrict__ x,
                                                   const float* __restrict__ g,
                                                   const float* __restrict__ b,
                                                   ushort_t* __restrict__ xn,
                                                   float2* __restrict__ csb,
                                                   const float* __restrict__ w0,
                                                   const float* __restrict__ w1,
                                                   const float* __restrict__ w2,
                                                   const float* __restrict__ w3,
                                                   ushort_t* __restrict__ wt) {
  __shared__ float red[8];
  __shared__ float tile[32][33];
  int blk = blockIdx.x, t = threadIdx.x;
  if (blk < 4096) {
    // LayerNorm row
    int row = blk;
    float4 v = ((const float4*)(x + (size_t)row * D_))[t];
    float s  = v.x + v.y + v.z + v.w;
    float s2 = v.x * v.x + v.y * v.y + v.z * v.z + v.w * v.w;
#pragma unroll
    for (int m = 1; m < 64; m <<= 1) { s += __shfl_xor(s, m); s2 += __shfl_xor(s2, m); }
    int w = t >> 6;
    if ((t & 63) == 0) { red[w] = s; red[4 + w] = s2; }
    __syncthreads();
    s  = red[0] + red[1] + red[2] + red[3];
    s2 = red[4] + red[5] + red[6] + red[7];
    float mean = s * (1.0f / D_);
    float var  = s2 * (1.0f / D_) - mean * mean;
    float rs   = rsqrtf(var + 1e-5f);
    float4 gg = ((const float4*)g)[t];
    float4 bb = ((const float4*)b)[t];
    unsigned long long pk =
        (unsigned long long)f2bf((v.x - mean) * rs * gg.x + bb.x)
      | ((unsigned long long)f2bf((v.y - mean) * rs * gg.y + bb.y) << 16)
      | ((unsigned long long)f2bf((v.z - mean) * rs * gg.z + bb.z) << 32)
      | ((unsigned long long)f2bf((v.w - mean) * rs * gg.w + bb.w) << 48);
    *(unsigned long long*)(xn + (size_t)row * D_ + t * 4) = pk;
  } else if (blk < 4160) {
    int idx = (blk - 4096) * 256 + t;
    int l = idx >> 5, i = idx & 31;
    float inv = powf(10000.0f, (-2.0f * (float)i) / 1024.0f);
    float ang = (float)l * inv;
    csb[idx] = make_float2(cosf(ang), sinf(ang));
  } else {
    int wb = blk - 4160;
    int z = wb >> 10;
    const float* W = (z == 0) ? w0 : (z == 1) ? w1 : (z == 2) ? w2 : w3;
    ushort_t* WT = wt + ((size_t)z << 20);
    int rem = wb & 1023;
    int by = rem >> 5, bx = rem & 31;
    int tx = t & 31, ty = t >> 5;  // 32 x 8
    int k0 = by * 32, n0 = bx * 32;
#pragma unroll
    for (int j = 0; j < 4; ++j)
      tile[ty + 8 * j][tx] = W[(size_t)(k0 + ty + 8 * j) * 1024 + n0 + tx];
    __syncthreads();
#pragma unroll
    for (int j = 0; j < 4; ++j)
      WT[(size_t)(n0 + ty + 8 * j) * 1024 + k0 + tx] = f2bf(tile[tx][ty + 8 * j]);
  }
}

// ---------------- Fused QKV GEMM: A[4096,1024] x WT[3072,1024]^T, 128x128 tile ----------------
// 2-phase double-buffered (T3 minimum): STAGE(next) issued BEFORE compute(cur),
// single barrier per iter (its implicit vmcnt(0) lands after the MFMA cluster).
// Epilogue by n-range: q=rope*0.125 ; k=rope ; v -> transposed vt
__global__ __launch_bounds__(256) void gemm_qkv_kernel(const ushort_t* __restrict__ xn,
                                                       const ushort_t* __restrict__ wt,
                                                       const float* __restrict__ bq,
                                                       const float* __restrict__ bk,
                                                       const float* __restrict__ bv,
                                                       ushort_t* __restrict__ qb,
                                                       ushort_t* __restrict__ kb,
                                                       ushort_t* __restrict__ vt,
                                                       const float2* __restrict__ csb) {
  __shared__ ushort_t As[2][128 * 64];
  __shared__ ushort_t Bs[2][128 * 64];
  int t = threadIdx.x, l = t & 63, w = t >> 6, lr = l & 15, lg = l >> 4;
  // XCD swizzle: 768 blocks, 8 XCDs, 96 logical tiles per XCD (x-major rows of 24)
  int hid = blockIdx.x;
  int lid = (hid & 7) * 96 + (hid >> 3);
  int bx = lid % 24, by = lid / 24;
  int m0 = by * 128;
  int n0g = bx * 128;          // global col in [0,3072)
  int z = n0g >> 10;
  int n0 = n0g & 1023;         // matrix-local col
  const float* bias = (z == 0) ? bq : (z == 1) ? bk : bv;
  int wr = w >> 1, wc = w & 1;
  const int srow = l >> 3;
  const int scol = ((l & 7) ^ (srow & 7)) * 8;  // pre-swizzled source col (BK=64)

#define STG(buf, k0)                                                              \
  {                                                                               \
    _Pragma("unroll")                                                             \
    for (int i = 0; i < 4; ++i) {                                                 \
      gl_lds16(&xn[(size_t)(m0 + w * 32 + i * 8 + srow) * 1024 + (k0) + scol],    \
               &As[buf][(w * 32 + i * 8) * 64]);                                  \
      gl_lds16(&wt[(size_t)(n0g + w * 32 + i * 8 + srow) * 1024 + (k0) + scol],   \
               &Bs[buf][(w * 32 + i * 8) * 64]);                                  \
    }                                                                             \
  }

  f32x4 acc[4][4] = {};
  STG(0, 0);
  __syncthreads();
  int cur = 0;
  for (int it = 0; it < 16; ++it) {
    if (it < 15) STG(cur ^ 1, (it + 1) * 64);
#pragma unroll
    for (int kk = 0; kk < 2; ++kk) {
      bf16x8 a[4], bfr[4];
#pragma unroll
      for (int mi = 0; mi < 4; ++mi)
        a[mi] = *(const bf16x8*)&As[cur][(wr * 64 + mi * 16 + lr) * 64 + (((kk * 4 + lg) ^ (lr & 7)) << 3)];
#pragma unroll
      for (int ni = 0; ni < 4; ++ni)
        bfr[ni] = *(const bf16x8*)&Bs[cur][(wc * 64 + ni * 16 + lr) * 64 + (((kk * 4 + lg) ^ (lr & 7)) << 3)];
#pragma unroll
      for (int mi = 0; mi < 4; ++mi)
#pragma unroll
        for (int ni = 0; ni < 4; ++ni)
          acc[mi][ni] = __builtin_amdgcn_mfma_f32_16x16x32_bf16(a[mi], bfr[ni], acc[mi][ni], 0, 0, 0);
    }
    __syncthreads();  // drains vmcnt(0): prefetch landed while MFMAs ran
    cur ^= 1;
  }
#undef STG

  if (z < 2) {
    // rope epilogue: pairs (even,odd col) sit in adjacent lanes -> shfl_xor(1)
    ushort_t* outp = (z == 0) ? qb : kb;
    const float sc = (z == 0) ? 0.125f : 1.0f;
#pragma unroll
    for (int mi = 0; mi < 4; ++mi) {
      int rowb = m0 + wr * 64 + mi * 16 + lg * 4;
#pragma unroll
      for (int ni = 0; ni < 4; ++ni) {
        int col = n0 + wc * 64 + ni * 16 + lr;
        float bvv = bias[col];
        int ii = (col & 63) >> 1;
        int codd = col & 1;
#pragma unroll
        for (int r = 0; r < 4; ++r) {
          float val = acc[mi][ni][r] + bvv;
          float par = __shfl_xor(val, 1);
          float2 cs = csb[((rowb + r) & 511) * 32 + ii];
          float y = codd ? (par * cs.y + val * cs.x) : (val * cs.x - par * cs.y);
          outp[(size_t)(rowb + r) * 1024 + col] = f2bf(y * sc);
        }
      }
    }
  } else {
    // V: write transposed to vt[(b*1024 + col)][l], 4 consecutive l per lane -> b64
#pragma unroll
    for (int mi = 0; mi < 4; ++mi) {
      int rowb = m0 + wr * 64 + mi * 16 + lg * 4;
      int bidx = rowb >> 9, l0 = rowb & 511;
#pragma unroll
      for (int ni = 0; ni < 4; ++ni) {
        int col = n0 + wc * 64 + ni * 16 + lr;
        float bvv = bias[col];
        unsigned long long pk =
            (unsigned long long)f2bf(acc[mi][ni][0] + bvv)
          | ((unsigned long long)f2bf(acc[mi][ni][1] + bvv) << 16)
          | ((unsigned long long)f2bf(acc[mi][ni][2] + bvv) << 32)
          | ((unsigned long long)f2bf(acc[mi][ni][3] + bvv) << 48);
        *(unsigned long long*)&vt[((size_t)(bidx << 10) + col) * 512 + l0] = pk;
      }
    }
  }
}

// ---------------- O GEMM: 64x128 tile, 2-phase dbuf, BK=64; fp32 out = acc+bias+res ----------------
__global__ __launch_bounds__(256) void gemm_o_kernel(const ushort_t* __restrict__ A,
                                                     const ushort_t* __restrict__ Bt,
                                                     const float* __restrict__ bias,
                                                     const float* __restrict__ res,
                                                     float* __restrict__ out) {
  __shared__ ushort_t As[2][64 * 64];
  __shared__ ushort_t Bs[2][128 * 64];
  int t = threadIdx.x, l = t & 63, w = t >> 6, lr = l & 15, lg = l >> 4;
  // XCD swizzle: 512 blocks, 64 per XCD
  int hid = blockIdx.x;
  int lid = (hid & 7) * 64 + (hid >> 3);
  int bx = lid & 7, by = lid >> 3;
  int m0 = by * 64, n0 = bx * 128;
  int wr = w >> 1, wc = w & 1;   // 2x2 waves: 32 rows x 64 cols each
  const int srow = l >> 3;
  const int scol = ((l & 7) ^ (srow & 7)) * 8;

#define STG(buf, k0)                                                              \
  {                                                                               \
    _Pragma("unroll")                                                             \
    for (int i = 0; i < 2; ++i)                                                   \
      gl_lds16(&A[(size_t)(m0 + w * 16 + i * 8 + srow) * 1024 + (k0) + scol],     \
               &As[buf][(w * 16 + i * 8) * 64]);                                  \
    _Pragma("unroll")                                                             \
    for (int i = 0; i < 4; ++i)                                                   \
      gl_lds16(&Bt[(size_t)(n0 + w * 32 + i * 8 + srow) * 1024 + (k0) + scol],    \
               &Bs[buf][(w * 32 + i * 8) * 64]);                                  \
  }

  f32x4 acc[2][4] = {};
  STG(0, 0);
  __syncthreads();
  int cur = 0;
  for (int it = 0; it < 16; ++it) {
    if (it < 15) STG(cur ^ 1, (it + 1) * 64);
#pragma unroll
    for (int kk = 0; kk < 2; ++kk) {
      bf16x8 a[2], bfr[4];
#pragma unroll
      for (int mi = 0; mi < 2; ++mi)
        a[mi] = *(const bf16x8*)&As[cur][(wr * 32 + mi * 16 + lr) * 64 + (((kk * 4 + lg) ^ (lr & 7)) << 3)];
#pragma unroll
      for (int ni = 0; ni < 4; ++ni)
        bfr[ni] = *(const bf16x8*)&Bs[cur][(wc * 64 + ni * 16 + lr) * 64 + (((kk * 4 + lg) ^ (lr & 7)) << 3)];
#pragma unroll
      for (int mi = 0; mi < 2; ++mi)
#pragma unroll
        for (int ni = 0; ni < 4; ++ni)
          acc[mi][ni] = __builtin_amdgcn_mfma_f32_16x16x32_bf16(a[mi], bfr[ni], acc[mi][ni], 0, 0, 0);
    }
    __syncthreads();
    cur ^= 1;
  }
#undef STG

#pragma unroll
  for (int mi = 0; mi < 2; ++mi) {
    int rowb = m0 + wr * 32 + mi * 16 + lg * 4;
#pragma unroll
    for (int ni = 0; ni < 4; ++ni) {
      int col = n0 + wc * 64 + ni * 16 + lr;
      float bvv = bias[col];
#pragma unroll
      for (int r = 0; r < 4; ++r) {
        size_t off = (size_t)(rowb + r) * 1024 + col;
        out[off] = acc[mi][ni][r] + bvv + res[off];
      }
    }
  }
}

// ---------------- Flash attention, swapped-operand form ----------------
// Grid: blk = qt*128 + bh (same bh -> same XCD). 4 waves x 32 q-rows = 128 q/block,
// 512 blocks (2/CU co-resident). K,Vt LDS-staged dbuf, lane-local softmax.
__global__ __launch_bounds__(256) void attn_kernel(const ushort_t* __restrict__ q,
                                                   const ushort_t* __restrict__ k,
                                                   const ushort_t* __restrict__ vt,
                                                   ushort_t* __restrict__ o) {
  __shared__ ushort_t Ks[2][64 * 64];
  __shared__ ushort_t Vs[2][64 * 64];
  __shared__ ushort_t Ps[4][2][16 * 64];
  int t = threadIdx.x, l = t & 63, w = t >> 6, lr = l & 15, lg = l >> 4;
  int blk = blockIdx.x;
  int bh = blk & 127, qt = blk >> 7;
  int b = bh >> 4, h = bh & 15;
  const int srow = l >> 3;
  const int scol = ((l & 7) ^ (srow & 7)) * 8;

  // Q fragments (B-operand: col=q=lr, k=d), held all kernel
  bf16x8 qf[2][2];
#pragma unroll
  for (int qm = 0; qm < 2; ++qm) {
    size_t qrow = (size_t)(b * 512 + qt * 128 + w * 32 + qm * 16 + lr);
#pragma unroll
    for (int kh = 0; kh < 2; ++kh)
      qf[qm][kh] = *(const bf16x8*)&q[qrow * 1024 + h * 64 + kh * 32 + lg * 8];
  }

  f32x4 oacc[2][4] = {};
  float mrun[2] = {-1e30f, -1e30f};
  float lrun[2] = {0.f, 0.f};

#define STAGE(buf, kv0)                                                              \
  {                                                                                  \
    _Pragma("unroll")                                                                \
    for (int j = 0; j < 2; ++j) {                                                    \
      gl_lds16(&k[(size_t)(b * 512 + (kv0) + w * 16 + j * 8 + srow) * 1024 + h * 64 + scol], \
               &Ks[buf][(w * 16 + j * 8) * 64]);                                     \
      gl_lds16(&vt[((size_t)bh * 64 + w * 16 + j * 8 + srow) * 512 + (kv0) + scol],  \
               &Vs[buf][(w * 16 + j * 8) * 64]);                                     \
    }                                                                                \
  }

  STAGE(0, 0);
  __syncthreads();
  int cur = 0;
  for (int it = 0; it < 8; ++it) {
    if (it < 7) { STAGE(cur ^ 1, (it + 1) * 64); }
    bf16x8 kf[2][4];
#pragma unroll
    for (int kh = 0; kh < 2; ++kh)
#pragma unroll
      for (int kn = 0; kn < 4; ++kn)
        kf[kh][kn] = *(const bf16x8*)&Ks[cur][(kn * 16 + lr) * 64 + (((kh * 4 + lg) ^ (lr & 7)) << 3)];

#pragma unroll
    for (int qm = 0; qm < 2; ++qm) {
      f32x4 st[4] = {};
#pragma unroll
      for (int kh = 0; kh < 2; ++kh)
#pragma unroll
        for (int kn = 0; kn < 4; ++kn)
          st[kn] = __builtin_amdgcn_mfma_f32_16x16x32_bf16(kf[kh][kn], qf[qm][kh], st[kn], 0, 0, 0);
      float mx = st[0][0];
#pragma unroll
      for (int kn = 0; kn < 4; ++kn)
#pragma unroll
        for (int r = 0; r < 4; ++r) mx = fmaxf(mx, st[kn][r]);
      mx = fmaxf(mx, __shfl_xor(mx, 16));
      mx = fmaxf(mx, __shfl_xor(mx, 32));
      float mn = mrun[qm], al = 1.0f;
      if (!__all(mx <= mrun[qm] + 8.0f)) {
        mn = fmaxf(mrun[qm], mx);
        al = __expf(mrun[qm] - mn);
        mrun[qm] = mn;
#pragma unroll
        for (int f = 0; f < 4; ++f) {
          oacc[qm][f][0] *= al; oacc[qm][f][1] *= al;
          oacc[qm][f][2] *= al; oacc[qm][f][3] *= al;
        }
      }
      float sm = 0.f;
#pragma unroll
      for (int kn = 0; kn < 4; ++kn) {
        float p0 = __expf(st[kn][0] - mn);
        float p1 = __expf(st[kn][1] - mn);
        float p2 = __expf(st[kn][2] - mn);
        float p3 = __expf(st[kn][3] - mn);
        sm += p0 + p1 + p2 + p3;
        int kvb = kn * 16 + 4 * lg;
        unsigned long long pk =
            (unsigned long long)f2bf(p0)
          | ((unsigned long long)f2bf(p1) << 16)
          | ((unsigned long long)f2bf(p2) << 32)
          | ((unsigned long long)f2bf(p3) << 48);
        *(unsigned long long*)&Ps[w][qm][lr * 64 + (((kvb >> 3) ^ (lr & 7)) << 3) + (kvb & 7)] = pk;
      }
      sm += __shfl_xor(sm, 16);
      sm += __shfl_xor(sm, 32);
      lrun[qm] = lrun[qm] * al + sm;
    }
    asm volatile("s_waitcnt lgkmcnt(0)" ::: "memory");
    __builtin_amdgcn_sched_barrier(0);
#pragma unroll
    for (int kk = 0; kk < 2; ++kk) {
      int sl = (((kk * 4 + lg) ^ (lr & 7)) << 3);
      bf16x8 pb[2];
#pragma unroll
      for (int qm = 0; qm < 2; ++qm)
        pb[qm] = *(const bf16x8*)&Ps[w][qm][lr * 64 + sl];
#pragma unroll
      for (int f = 0; f < 4; ++f) {
        bf16x8 vf = *(const bf16x8*)&Vs[cur][(f * 16 + lr) * 64 + sl];
#pragma unroll
        for (int qm = 0; qm < 2; ++qm)
          oacc[qm][f] = __builtin_amdgcn_mfma_f32_16x16x32_bf16(vf, pb[qm], oacc[qm][f], 0, 0, 0);
      }
    }
    __syncthreads();
    cur ^= 1;
  }
#pragma unroll
  for (int qm = 0; qm < 2; ++qm) {
    float inv = 1.0f / lrun[qm];
    size_t qrow = (size_t)(b * 512 + qt * 128 + w * 32 + qm * 16 + lr);
#pragma unroll
    for (int f = 0; f < 4; ++f) {
      unsigned long long pk =
          (unsigned long long)f2bf(oacc[qm][f][0] * inv)
        | ((unsigned long long)f2bf(oacc[qm][f][1] * inv) << 16)
        | ((unsigned long long)f2bf(oacc[qm][f][2] * inv) << 32)
        | ((unsigned long long)f2bf(oacc[qm][f][3] * inv) << 48);
      *(unsigned long long*)&o[qrow * 1024 + h * 64 + f * 16 + 4 * lg] = pk;
    }
  }
#undef STAGE
}

// ---------------- launch ----------------
extern "C" void kernel_launch(void* const* d_in, const int* in_sizes, int n_in,
                              void* d_out, int out_size, void* d_ws, size_t ws_size,
                              hipStream_t stream) {
  const float* input_ids = (const float*)d_in[0];
  const float* Wq = (const float*)d_in[1];
  const float* bq = (const float*)d_in[2];
  const float* Wk = (const float*)d_in[3];
  const float* bk = (const float*)d_in[4];
  const float* Wv = (const float*)d_in[5];
  const float* bv = (const float*)d_in[6];
  const float* Wo = (const float*)d_in[7];
  const float* bo = (const float*)d_in[8];
  const float* g_attn = (const float*)d_in[13];
  const float* b_attn = (const float*)d_in[14];
  float* out = (float*)d_out;

  char* ws = (char*)d_ws;
  const size_t MB = 1024 * 1024;
  ushort_t* wt = (ushort_t*)(ws);             // 8MB: Wq^T,Wk^T,Wv^T,Wo^T bf16 (contiguous)
  ushort_t* xn = (ushort_t*)(ws + 8 * MB);    // 8MB: LN out, later attn O
  ushort_t* qb = (ushort_t*)(ws + 16 * MB);   // 8MB
  ushort_t* kb = (ushort_t*)(ws + 24 * MB);   // 8MB
  ushort_t* vt = (ushort_t*)(ws + 32 * MB);   // 8MB: V transposed [b*1024+col][l]
  float2* csb  = (float2*)(ws + 40 * MB);     // 128KB interleaved cos/sin

  prep_kernel<<<8256, 256, 0, stream>>>(input_ids, g_attn, b_attn, xn, csb,
                                        Wq, Wk, Wv, Wo, wt);
  gemm_qkv_kernel<<<768, 256, 0, stream>>>(xn, wt, bq, bk, bv, qb, kb, vt, csb);
  attn_kernel<<<512, 256, 0, stream>>>(qb, kb, vt, xn);  // xn <- O (bf16)
  gemm_o_kernel<<<512, 256, 0, stream>>>(xn, wt + 3 * MB, bo, input_ids, out);
}

// Round 7
// 97.295 us; speedup vs baseline: 1.1562x; 1.1562x over previous
//
#include <hip/hip_runtime.h>

typedef unsigned short ushort_t;
typedef short bf16x8 __attribute__((ext_vector_type(8)));
typedef float f32x4 __attribute__((ext_vector_type(4)));

#define B_ 8
#define L_ 512
#define D_ 1024
#define H_ 16
#define M_ 4096

__device__ __forceinline__ ushort_t f2bf(float f) {
  union { float f; unsigned u; } v; v.f = f;
  unsigned r = v.u + 0x7FFFu + ((v.u >> 16) & 1u);
  return (ushort_t)(r >> 16);
}

// global -> LDS direct (16B per lane, dest = wave-uniform base + lane*16)
__device__ __forceinline__ void gl_lds16(const ushort_t* g, ushort_t* s) {
  __builtin_amdgcn_global_load_lds((const __attribute__((address_space(1))) void*)(g),
                                   (__attribute__((address_space(3))) void*)(s), 16, 0, 0);
}

// ---------------- fused preamble: LN (blocks 0..4095), cos/sin table (4096..4159),
// ---------------- weight transpose+bf16 (4160..8255) ----------------
__global__ __launch_bounds__(256) void prep_kernel(const float* __restrict__ x,
                                                   const float* __restrict__ g,
                                                   const float* __restrict__ b,
                                                   ushort_t* __restrict__ xn,
                                                   float2* __restrict__ csb,
                                                   const float* __restrict__ w0,
                                                   const float* __restrict__ w1,
                                                   const float* __restrict__ w2,
                                                   const float* __restrict__ w3,
                                                   ushort_t* __restrict__ wt) {
  __shared__ float red[8];
  __shared__ float tile[32][33];
  int blk = blockIdx.x, t = threadIdx.x;
  if (blk < 4096) {
    int row = blk;
    float4 v = ((const float4*)(x + (size_t)row * D_))[t];
    float s  = v.x + v.y + v.z + v.w;
    float s2 = v.x * v.x + v.y * v.y + v.z * v.z + v.w * v.w;
#pragma unroll
    for (int m = 1; m < 64; m <<= 1) { s += __shfl_xor(s, m); s2 += __shfl_xor(s2, m); }
    int w = t >> 6;
    if ((t & 63) == 0) { red[w] = s; red[4 + w] = s2; }
    __syncthreads();
    s  = red[0] + red[1] + red[2] + red[3];
    s2 = red[4] + red[5] + red[6] + red[7];
    float mean = s * (1.0f / D_);
    float var  = s2 * (1.0f / D_) - mean * mean;
    float rs   = rsqrtf(var + 1e-5f);
    float4 gg = ((const float4*)g)[t];
    float4 bb = ((const float4*)b)[t];
    unsigned long long pk =
        (unsigned long long)f2bf((v.x - mean) * rs * gg.x + bb.x)
      | ((unsigned long long)f2bf((v.y - mean) * rs * gg.y + bb.y) << 16)
      | ((unsigned long long)f2bf((v.z - mean) * rs * gg.z + bb.z) << 32)
      | ((unsigned long long)f2bf((v.w - mean) * rs * gg.w + bb.w) << 48);
    *(unsigned long long*)(xn + (size_t)row * D_ + t * 4) = pk;
  } else if (blk < 4160) {
    int idx = (blk - 4096) * 256 + t;
    int l = idx >> 5, i = idx & 31;
    float inv = powf(10000.0f, (-2.0f * (float)i) / 1024.0f);
    float ang = (float)l * inv;
    csb[idx] = make_float2(cosf(ang), sinf(ang));
  } else {
    int wb = blk - 4160;
    int z = wb >> 10;
    const float* W = (z == 0) ? w0 : (z == 1) ? w1 : (z == 2) ? w2 : w3;
    ushort_t* WT = wt + ((size_t)z << 20);
    int rem = wb & 1023;
    int by = rem >> 5, bx = rem & 31;
    int tx = t & 31, ty = t >> 5;  // 32 x 8
    int k0 = by * 32, n0 = bx * 32;
#pragma unroll
    for (int j = 0; j < 4; ++j)
      tile[ty + 8 * j][tx] = W[(size_t)(k0 + ty + 8 * j) * 1024 + n0 + tx];
    __syncthreads();
#pragma unroll
    for (int j = 0; j < 4; ++j)
      WT[(size_t)(n0 + ty + 8 * j) * 1024 + k0 + tx] = f2bf(tile[tx][ty + 8 * j]);
  }
}

// ---------------- Fused QKV GEMM: 256x256 tile, BK=64, 4-phase/K-tile split ----------------
// 512 threads = 8 waves (2 wr x 4 wc), per-wave 128x64 output, acc[8][4].
// Phase: 12 ds_read_b128 (swizzled) | stage next K-tile (phases 0-1) | s_barrier |
//        setprio(1) 16 MFMA setprio(0) | s_barrier.  One vmcnt(0) per K-tile boundary.
// Epilogue by n-range: q=rope*0.125 ; k=rope ; v -> transposed vt
__global__ __launch_bounds__(512, 2) void gemm_qkv_kernel(const ushort_t* __restrict__ xn,
                                                          const ushort_t* __restrict__ wt,
                                                          const float* __restrict__ bq,
                                                          const float* __restrict__ bk,
                                                          const float* __restrict__ bv,
                                                          ushort_t* __restrict__ qb,
                                                          ushort_t* __restrict__ kb,
                                                          ushort_t* __restrict__ vt,
                                                          const float2* __restrict__ csb) {
  __shared__ ushort_t As[2][256 * 64];
  __shared__ ushort_t Bs[2][256 * 64];
  int t = threadIdx.x, l = t & 63, w = t >> 6, lr = l & 15, lg = l >> 4;
  // XCD swizzle: 192 blocks = 8 XCDs x 24
  int hid = blockIdx.x;
  int lid = (hid & 7) * 24 + (hid >> 3);
  int by = lid / 12, bx = lid % 12;
  int m0 = by * 256;
  int n0g = bx * 256;
  int z = n0g >> 10;
  int n0 = n0g & 1023;
  const float* bias = (z == 0) ? bq : (z == 1) ? bk : bv;
  int wr = w >> 2, wc = w & 3;
  const int sr8 = l >> 3;                      // 0..7 row-in-band
  const int scol = ((l & 7) ^ sr8) * 8;        // pre-swizzled source col

  // stage one 64-row chunk (8 rows per wave), rb in {0,64,128,192}
#define STGA(buf, rb, k0)                                                           \
  gl_lds16(&xn[(size_t)(m0 + (rb) + w * 8 + sr8) * 1024 + (k0) + scol],             \
           &As[buf][((rb) + w * 8) * 64]);
#define STGB(buf, rb, k0)                                                           \
  gl_lds16(&wt[(size_t)(n0g + (rb) + w * 8 + sr8) * 1024 + (k0) + scol],            \
           &Bs[buf][((rb) + w * 8) * 64]);

  f32x4 acc[8][4] = {};

  // prologue: stage K-tile 0 into buf 0
  STGA(0, 0, 0) STGA(0, 64, 0) STGA(0, 128, 0) STGA(0, 192, 0)
  STGB(0, 0, 0) STGB(0, 64, 0) STGB(0, 128, 0) STGB(0, 192, 0)
  asm volatile("s_waitcnt vmcnt(0)" ::: "memory");
  __builtin_amdgcn_s_barrier();

  for (int j = 0; j < 16; ++j) {
    int cur = j & 1, nxt = cur ^ 1, kn = (j + 1) * 64;
#pragma unroll
    for (int q = 0; q < 4; ++q) {
      const int mh = q >> 1, nh = q & 1;
      bf16x8 a[4][2], bb[2][2];
#pragma unroll
      for (int mi = 0; mi < 4; ++mi)
#pragma unroll
        for (int kk = 0; kk < 2; ++kk)
          a[mi][kk] = *(const bf16x8*)&As[cur][(wr * 128 + (mh * 4 + mi) * 16 + lr) * 64 +
                                              (((kk * 4 + lg) ^ (lr & 7)) << 3)];
#pragma unroll
      for (int ni = 0; ni < 2; ++ni)
#pragma unroll
        for (int kk = 0; kk < 2; ++kk)
          bb[ni][kk] = *(const bf16x8*)&Bs[cur][(wc * 64 + (nh * 2 + ni) * 16 + lr) * 64 +
                                               (((kk * 4 + lg) ^ (lr & 7)) << 3)];
      if (j < 15) {
        if (q == 0) { STGA(nxt, 0, kn) STGA(nxt, 64, kn) STGA(nxt, 128, kn) STGA(nxt, 192, kn) }
        else if (q == 1) { STGB(nxt, 0, kn) STGB(nxt, 64, kn) STGB(nxt, 128, kn) STGB(nxt, 192, kn) }
      }
      __builtin_amdgcn_s_barrier();
      __builtin_amdgcn_s_setprio(1);
#pragma unroll
      for (int kk = 0; kk < 2; ++kk)
#pragma unroll
        for (int mi = 0; mi < 4; ++mi)
#pragma unroll
          for (int ni = 0; ni < 2; ++ni)
            acc[mh * 4 + mi][nh * 2 + ni] = __builtin_amdgcn_mfma_f32_16x16x32_bf16(
                a[mi][kk], bb[ni][kk], acc[mh * 4 + mi][nh * 2 + ni], 0, 0, 0);
      __builtin_amdgcn_s_setprio(0);
      if (q == 3 && j < 15) asm volatile("s_waitcnt vmcnt(0)" ::: "memory");
      __builtin_amdgcn_s_barrier();
    }
  }
#undef STGA
#undef STGB

  if (z < 2) {
    // rope epilogue: pairs (even,odd col) sit in adjacent lanes -> shfl_xor(1)
    ushort_t* outp = (z == 0) ? qb : kb;
    const float sc = (z == 0) ? 0.125f : 1.0f;
#pragma unroll
    for (int mi = 0; mi < 8; ++mi) {
      int rowb = m0 + wr * 128 + mi * 16 + lg * 4;
#pragma unroll
      for (int ni = 0; ni < 4; ++ni) {
        int col = n0 + wc * 64 + ni * 16 + lr;
        float bvv = bias[col];
        int ii = (col & 63) >> 1;
        int codd = col & 1;
#pragma unroll
        for (int r = 0; r < 4; ++r) {
          float val = acc[mi][ni][r] + bvv;
          float par = __shfl_xor(val, 1);
          float2 cs = csb[((rowb + r) & 511) * 32 + ii];
          float y = codd ? (par * cs.y + val * cs.x) : (val * cs.x - par * cs.y);
          outp[(size_t)(rowb + r) * 1024 + col] = f2bf(y * sc);
        }
      }
    }
  } else {
    // V: write transposed to vt[(b*1024 + col)][l], 4 consecutive l per lane -> b64
#pragma unroll
    for (int mi = 0; mi < 8; ++mi) {
      int rowb = m0 + wr * 128 + mi * 16 + lg * 4;
      int bidx = rowb >> 9, l0 = rowb & 511;
#pragma unroll
      for (int ni = 0; ni < 4; ++ni) {
        int col = n0 + wc * 64 + ni * 16 + lr;
        float bvv = bias[col];
        unsigned long long pk =
            (unsigned long long)f2bf(acc[mi][ni][0] + bvv)
          | ((unsigned long long)f2bf(acc[mi][ni][1] + bvv) << 16)
          | ((unsigned long long)f2bf(acc[mi][ni][2] + bvv) << 32)
          | ((unsigned long long)f2bf(acc[mi][ni][3] + bvv) << 48);
        *(unsigned long long*)&vt[((size_t)(bidx << 10) + col) * 512 + l0] = pk;
      }
    }
  }
}

// ---------------- O GEMM: 64x128 tile (512 blocks), BK=64, single-buffer; fp32 out ----------------
__global__ __launch_bounds__(256) void gemm_o_kernel(const ushort_t* __restrict__ A,
                                                     const ushort_t* __restrict__ Bt,
                                                     const float* __restrict__ bias,
                                                     const float* __restrict__ res,
                                                     float* __restrict__ out) {
  __shared__ ushort_t As[64 * 64];
  __shared__ ushort_t Bs[128 * 64];
  int t = threadIdx.x, l = t & 63, w = t >> 6, lr = l & 15, lg = l >> 4;
  int hid = blockIdx.x;
  int lid = (hid & 7) * 64 + (hid >> 3);
  int bx = lid & 7, by = lid >> 3;
  int m0 = by * 64, n0 = bx * 128;
  int wr = w >> 1, wc = w & 1;   // 2x2 waves: 32 rows x 64 cols each
  const int srow = l >> 3;
  const int scol = ((l & 7) ^ (srow & 7)) * 8;

  f32x4 acc[2][4] = {};

  for (int k0 = 0; k0 < 1024; k0 += 64) {
#pragma unroll
    for (int i = 0; i < 2; ++i)
      gl_lds16(&A[(size_t)(m0 + w * 16 + i * 8 + srow) * 1024 + k0 + scol],
               &As[(w * 16 + i * 8) * 64]);
#pragma unroll
    for (int i = 0; i < 4; ++i)
      gl_lds16(&Bt[(size_t)(n0 + w * 32 + i * 8 + srow) * 1024 + k0 + scol],
               &Bs[(w * 32 + i * 8) * 64]);
    __syncthreads();
#pragma unroll
    for (int kk = 0; kk < 2; ++kk) {
      bf16x8 a[2], bfr[4];
#pragma unroll
      for (int mi = 0; mi < 2; ++mi)
        a[mi] = *(const bf16x8*)&As[(wr * 32 + mi * 16 + lr) * 64 + (((kk * 4 + lg) ^ (lr & 7)) << 3)];
#pragma unroll
      for (int ni = 0; ni < 4; ++ni)
        bfr[ni] = *(const bf16x8*)&Bs[(wc * 64 + ni * 16 + lr) * 64 + (((kk * 4 + lg) ^ (lr & 7)) << 3)];
#pragma unroll
      for (int mi = 0; mi < 2; ++mi)
#pragma unroll
        for (int ni = 0; ni < 4; ++ni)
          acc[mi][ni] = __builtin_amdgcn_mfma_f32_16x16x32_bf16(a[mi], bfr[ni], acc[mi][ni], 0, 0, 0);
    }
    __syncthreads();
  }

#pragma unroll
  for (int mi = 0; mi < 2; ++mi) {
    int rowb = m0 + wr * 32 + mi * 16 + lg * 4;
#pragma unroll
    for (int ni = 0; ni < 4; ++ni) {
      int col = n0 + wc * 64 + ni * 16 + lr;
      float bvv = bias[col];
#pragma unroll
      for (int r = 0; r < 4; ++r) {
        size_t off = (size_t)(rowb + r) * 1024 + col;
        out[off] = acc[mi][ni][r] + bvv + res[off];
      }
    }
  }
}

// ---------------- Flash attention, swapped-operand form (round-5, verified) ----------------
__global__ __launch_bounds__(256) void attn_kernel(const ushort_t* __restrict__ q,
                                                   const ushort_t* __restrict__ k,
                                                   const ushort_t* __restrict__ vt,
                                                   ushort_t* __restrict__ o) {
  __shared__ ushort_t Ks[2][64 * 64];
  __shared__ ushort_t Vs[2][64 * 64];
  __shared__ ushort_t Ps[4][2][16 * 64];
  int t = threadIdx.x, l = t & 63, w = t >> 6, lr = l & 15, lg = l >> 4;
  int blk = blockIdx.x;
  int bh = blk & 127, qt = blk >> 7;
  int b = bh >> 4, h = bh & 15;
  const int srow = l >> 3;
  const int scol = ((l & 7) ^ (srow & 7)) * 8;

  bf16x8 qf[2][2];
#pragma unroll
  for (int qm = 0; qm < 2; ++qm) {
    size_t qrow = (size_t)(b * 512 + qt * 128 + w * 32 + qm * 16 + lr);
#pragma unroll
    for (int kh = 0; kh < 2; ++kh)
      qf[qm][kh] = *(const bf16x8*)&q[qrow * 1024 + h * 64 + kh * 32 + lg * 8];
  }

  f32x4 oacc[2][4] = {};
  float mrun[2] = {-1e30f, -1e30f};
  float lrun[2] = {0.f, 0.f};

#define STAGE(buf, kv0)                                                              \
  {                                                                                  \
    _Pragma("unroll")                                                                \
    for (int j = 0; j < 2; ++j) {                                                    \
      gl_lds16(&k[(size_t)(b * 512 + (kv0) + w * 16 + j * 8 + srow) * 1024 + h * 64 + scol], \
               &Ks[buf][(w * 16 + j * 8) * 64]);                                     \
      gl_lds16(&vt[((size_t)bh * 64 + w * 16 + j * 8 + srow) * 512 + (kv0) + scol],  \
               &Vs[buf][(w * 16 + j * 8) * 64]);                                     \
    }                                                                                \
  }

  STAGE(0, 0);
  __syncthreads();
  int cur = 0;
  for (int it = 0; it < 8; ++it) {
    if (it < 7) { STAGE(cur ^ 1, (it + 1) * 64); }
    bf16x8 kf[2][4];
#pragma unroll
    for (int kh = 0; kh < 2; ++kh)
#pragma unroll
      for (int kn = 0; kn < 4; ++kn)
        kf[kh][kn] = *(const bf16x8*)&Ks[cur][(kn * 16 + lr) * 64 + (((kh * 4 + lg) ^ (lr & 7)) << 3)];

#pragma unroll
    for (int qm = 0; qm < 2; ++qm) {
      f32x4 st[4] = {};
#pragma unroll
      for (int kh = 0; kh < 2; ++kh)
#pragma unroll
        for (int kn = 0; kn < 4; ++kn)
          st[kn] = __builtin_amdgcn_mfma_f32_16x16x32_bf16(kf[kh][kn], qf[qm][kh], st[kn], 0, 0, 0);
      float mx = st[0][0];
#pragma unroll
      for (int kn = 0; kn < 4; ++kn)
#pragma unroll
        for (int r = 0; r < 4; ++r) mx = fmaxf(mx, st[kn][r]);
      mx = fmaxf(mx, __shfl_xor(mx, 16));
      mx = fmaxf(mx, __shfl_xor(mx, 32));
      float mn = mrun[qm], al = 1.0f;
      if (!__all(mx <= mrun[qm] + 8.0f)) {
        mn = fmaxf(mrun[qm], mx);
        al = __expf(mrun[qm] - mn);
        mrun[qm] = mn;
#pragma unroll
        for (int f = 0; f < 4; ++f) {
          oacc[qm][f][0] *= al; oacc[qm][f][1] *= al;
          oacc[qm][f][2] *= al; oacc[qm][f][3] *= al;
        }
      }
      float sm = 0.f;
#pragma unroll
      for (int kn = 0; kn < 4; ++kn) {
        float p0 = __expf(st[kn][0] - mn);
        float p1 = __expf(st[kn][1] - mn);
        float p2 = __expf(st[kn][2] - mn);
        float p3 = __expf(st[kn][3] - mn);
        sm += p0 + p1 + p2 + p3;
        int kvb = kn * 16 + 4 * lg;
        unsigned long long pk =
            (unsigned long long)f2bf(p0)
          | ((unsigned long long)f2bf(p1) << 16)
          | ((unsigned long long)f2bf(p2) << 32)
          | ((unsigned long long)f2bf(p3) << 48);
        *(unsigned long long*)&Ps[w][qm][lr * 64 + (((kvb >> 3) ^ (lr & 7)) << 3) + (kvb & 7)] = pk;
      }
      sm += __shfl_xor(sm, 16);
      sm += __shfl_xor(sm, 32);
      lrun[qm] = lrun[qm] * al + sm;
    }
    asm volatile("s_waitcnt lgkmcnt(0)" ::: "memory");
    __builtin_amdgcn_sched_barrier(0);
#pragma unroll
    for (int kk = 0; kk < 2; ++kk) {
      int sl = (((kk * 4 + lg) ^ (lr & 7)) << 3);
      bf16x8 pb[2];
#pragma unroll
      for (int qm = 0; qm < 2; ++qm)
        pb[qm] = *(const bf16x8*)&Ps[w][qm][lr * 64 + sl];
#pragma unroll
      for (int f = 0; f < 4; ++f) {
        bf16x8 vf = *(const bf16x8*)&Vs[cur][(f * 16 + lr) * 64 + sl];
#pragma unroll
        for (int qm = 0; qm < 2; ++qm)
          oacc[qm][f] = __builtin_amdgcn_mfma_f32_16x16x32_bf16(vf, pb[qm], oacc[qm][f], 0, 0, 0);
      }
    }
    __syncthreads();
    cur ^= 1;
  }
#pragma unroll
  for (int qm = 0; qm < 2; ++qm) {
    float inv = 1.0f / lrun[qm];
    size_t qrow = (size_t)(b * 512 + qt * 128 + w * 32 + qm * 16 + lr);
#pragma unroll
    for (int f = 0; f < 4; ++f) {
      unsigned long long pk =
          (unsigned long long)f2bf(oacc[qm][f][0] * inv)
        | ((unsigned long long)f2bf(oacc[qm][f][1] * inv) << 16)
        | ((unsigned long long)f2bf(oacc[qm][f][2] * inv) << 32)
        | ((unsigned long long)f2bf(oacc[qm][f][3] * inv) << 48);
      *(unsigned long long*)&o[qrow * 1024 + h * 64 + f * 16 + 4 * lg] = pk;
    }
  }
#undef STAGE
}

// ---------------- launch ----------------
extern "C" void kernel_launch(void* const* d_in, const int* in_sizes, int n_in,
                              void* d_out, int out_size, void* d_ws, size_t ws_size,
                              hipStream_t stream) {
  const float* input_ids = (const float*)d_in[0];
  const float* Wq = (const float*)d_in[1];
  const float* bq = (const float*)d_in[2];
  const float* Wk = (const float*)d_in[3];
  const float* bk = (const float*)d_in[4];
  const float* Wv = (const float*)d_in[5];
  const float* bv = (const float*)d_in[6];
  const float* Wo = (const float*)d_in[7];
  const float* bo = (const float*)d_in[8];
  const float* g_attn = (const float*)d_in[13];
  const float* b_attn = (const float*)d_in[14];
  float* out = (float*)d_out;

  char* ws = (char*)d_ws;
  const size_t MB = 1024 * 1024;
  ushort_t* wt = (ushort_t*)(ws);             // 8MB: Wq^T,Wk^T,Wv^T,Wo^T bf16 (contiguous)
  ushort_t* xn = (ushort_t*)(ws + 8 * MB);    // 8MB: LN out, later attn O
  ushort_t* qb = (ushort_t*)(ws + 16 * MB);   // 8MB
  ushort_t* kb = (ushort_t*)(ws + 24 * MB);   // 8MB
  ushort_t* vt = (ushort_t*)(ws + 32 * MB);   // 8MB: V transposed [b*1024+col][l]
  float2* csb  = (float2*)(ws + 40 * MB);     // 128KB interleaved cos/sin

  prep_kernel<<<8256, 256, 0, stream>>>(input_ids, g_attn, b_attn, xn, csb,
                                        Wq, Wk, Wv, Wo, wt);
  gemm_qkv_kernel<<<192, 512, 0, stream>>>(xn, wt, bq, bk, bv, qb, kb, vt, csb);
  attn_kernel<<<512, 256, 0, stream>>>(qb, kb, vt, xn);  // xn <- O (bf16)
  gemm_o_kernel<<<512, 256, 0, stream>>>(xn, wt + 3 * MB, bo, input_ids, out);
}

// Round 8
// 96.991 us; speedup vs baseline: 1.1598x; 1.0031x over previous
//
#include <hip/hip_runtime.h>

typedef unsigned short ushort_t;
typedef short bf16x8 __attribute__((ext_vector_type(8)));
typedef float f32x4 __attribute__((ext_vector_type(4)));

#define B_ 8
#define L_ 512
#define D_ 1024
#define H_ 16
#define M_ 4096

__device__ __forceinline__ ushort_t f2bf(float f) {
  union { float f; unsigned u; } v; v.f = f;
  unsigned r = v.u + 0x7FFFu + ((v.u >> 16) & 1u);
  return (ushort_t)(r >> 16);
}

// global -> LDS direct (16B per lane, dest = wave-uniform base + lane*16)
__device__ __forceinline__ void gl_lds16(const ushort_t* g, ushort_t* s) {
  __builtin_amdgcn_global_load_lds((const __attribute__((address_space(1))) void*)(g),
                                   (__attribute__((address_space(3))) void*)(s), 16, 0, 0);
}

// ---------------- fused preamble: LN (blocks 0..4095), cos/sin table (4096..4159),
// ---------------- weight transpose+bf16 (4160..8255) ----------------
__global__ __launch_bounds__(256) void prep_kernel(const float* __restrict__ x,
                                                   const float* __restrict__ g,
                                                   const float* __restrict__ b,
                                                   ushort_t* __restrict__ xn,
                                                   float2* __restrict__ csb,
                                                   const float* __restrict__ w0,
                                                   const float* __restrict__ w1,
                                                   const float* __restrict__ w2,
                                                   const float* __restrict__ w3,
                                                   ushort_t* __restrict__ wt) {
  __shared__ float red[8];
  __shared__ float tile[32][33];
  int blk = blockIdx.x, t = threadIdx.x;
  if (blk < 4096) {
    int row = blk;
    float4 v = ((const float4*)(x + (size_t)row * D_))[t];
    float s  = v.x + v.y + v.z + v.w;
    float s2 = v.x * v.x + v.y * v.y + v.z * v.z + v.w * v.w;
#pragma unroll
    for (int m = 1; m < 64; m <<= 1) { s += __shfl_xor(s, m); s2 += __shfl_xor(s2, m); }
    int w = t >> 6;
    if ((t & 63) == 0) { red[w] = s; red[4 + w] = s2; }
    __syncthreads();
    s  = red[0] + red[1] + red[2] + red[3];
    s2 = red[4] + red[5] + red[6] + red[7];
    float mean = s * (1.0f / D_);
    float var  = s2 * (1.0f / D_) - mean * mean;
    float rs   = rsqrtf(var + 1e-5f);
    float4 gg = ((const float4*)g)[t];
    float4 bb = ((const float4*)b)[t];
    unsigned long long pk =
        (unsigned long long)f2bf((v.x - mean) * rs * gg.x + bb.x)
      | ((unsigned long long)f2bf((v.y - mean) * rs * gg.y + bb.y) << 16)
      | ((unsigned long long)f2bf((v.z - mean) * rs * gg.z + bb.z) << 32)
      | ((unsigned long long)f2bf((v.w - mean) * rs * gg.w + bb.w) << 48);
    *(unsigned long long*)(xn + (size_t)row * D_ + t * 4) = pk;
  } else if (blk < 4160) {
    int idx = (blk - 4096) * 256 + t;
    int l = idx >> 5, i = idx & 31;
    float inv = powf(10000.0f, (-2.0f * (float)i) / 1024.0f);
    float ang = (float)l * inv;
    csb[idx] = make_float2(cosf(ang), sinf(ang));
  } else {
    int wb = blk - 4160;
    int z = wb >> 10;
    const float* W = (z == 0) ? w0 : (z == 1) ? w1 : (z == 2) ? w2 : w3;
    ushort_t* WT = wt + ((size_t)z << 20);
    int rem = wb & 1023;
    int by = rem >> 5, bx = rem & 31;
    int tx = t & 31, ty = t >> 5;  // 32 x 8
    int k0 = by * 32, n0 = bx * 32;
#pragma unroll
    for (int j = 0; j < 4; ++j)
      tile[ty + 8 * j][tx] = W[(size_t)(k0 + ty + 8 * j) * 1024 + n0 + tx];
    __syncthreads();
#pragma unroll
    for (int j = 0; j < 4; ++j)
      WT[(size_t)(n0 + ty + 8 * j) * 1024 + k0 + tx] = f2bf(tile[tx][ty + 8 * j]);
  }
}

// ---------------- Fused QKV GEMM: 256x256 tile, BK=64, one barrier per K-tile ----------------
// 512 threads = 8 waves (2 wr x 4 wc), per-wave 128x64 output, acc[8][4].
// Per K-tile: read bb[4][2] once (8 ds_reads) | stage next K-tile (8 gl_lds) |
// 4 clusters of {4 a-reads + 16 MFMA} (compiler overlaps reads with prev cluster's MFMAs) |
// vmcnt(0) | s_barrier.  24 ds_read_b128 per wave per K-tile (was 48), 16 barriers (was 128).
// Epilogue by n-range: q=rope*0.125 ; k=rope ; v -> transposed vt
__global__ __launch_bounds__(512, 2) void gemm_qkv_kernel(const ushort_t* __restrict__ xn,
                                                          const ushort_t* __restrict__ wt,
                                                          const float* __restrict__ bq,
                                                          const float* __restrict__ bk,
                                                          const float* __restrict__ bv,
                                                          ushort_t* __restrict__ qb,
                                                          ushort_t* __restrict__ kb,
                                                          ushort_t* __restrict__ vt,
                                                          const float2* __restrict__ csb) {
  __shared__ ushort_t As[2][256 * 64];
  __shared__ ushort_t Bs[2][256 * 64];
  int t = threadIdx.x, l = t & 63, w = t >> 6, lr = l & 15, lg = l >> 4;
  // XCD swizzle: 192 blocks = 8 XCDs x 24
  int hid = blockIdx.x;
  int lid = (hid & 7) * 24 + (hid >> 3);
  int by = lid / 12, bx = lid % 12;
  int m0 = by * 256;
  int n0g = bx * 256;
  int z = n0g >> 10;
  int n0 = n0g & 1023;
  const float* bias = (z == 0) ? bq : (z == 1) ? bk : bv;
  int wr = w >> 2, wc = w & 3;
  const int sr8 = l >> 3;                      // 0..7 row-in-band
  const int scol = ((l & 7) ^ sr8) * 8;        // pre-swizzled source col

  // stage one 64-row chunk (8 rows per wave), rb in {0,64,128,192}
#define STGA(buf, rb, k0)                                                           \
  gl_lds16(&xn[(size_t)(m0 + (rb) + w * 8 + sr8) * 1024 + (k0) + scol],             \
           &As[buf][((rb) + w * 8) * 64]);
#define STGB(buf, rb, k0)                                                           \
  gl_lds16(&wt[(size_t)(n0g + (rb) + w * 8 + sr8) * 1024 + (k0) + scol],            \
           &Bs[buf][((rb) + w * 8) * 64]);

  f32x4 acc[8][4] = {};

  // prologue: stage K-tile 0 into buf 0
  STGA(0, 0, 0) STGA(0, 64, 0) STGA(0, 128, 0) STGA(0, 192, 0)
  STGB(0, 0, 0) STGB(0, 64, 0) STGB(0, 128, 0) STGB(0, 192, 0)
  asm volatile("s_waitcnt vmcnt(0)" ::: "memory");
  __builtin_amdgcn_s_barrier();

  for (int j = 0; j < 16; ++j) {
    int cur = j & 1, nxt = cur ^ 1, kn = (j + 1) * 64;
    // B fragments for the whole K-tile (held in regs, shared by all 4 clusters)
    bf16x8 bb[4][2];
#pragma unroll
    for (int ni = 0; ni < 4; ++ni)
#pragma unroll
      for (int kk = 0; kk < 2; ++kk)
        bb[ni][kk] = *(const bf16x8*)&Bs[cur][(wc * 64 + ni * 16 + lr) * 64 +
                                             (((kk * 4 + lg) ^ (lr & 7)) << 3)];
    if (j < 15) {
      STGA(nxt, 0, kn) STGA(nxt, 64, kn) STGA(nxt, 128, kn) STGA(nxt, 192, kn)
      STGB(nxt, 0, kn) STGB(nxt, 64, kn) STGB(nxt, 128, kn) STGB(nxt, 192, kn)
    }
    __builtin_amdgcn_s_setprio(1);
#pragma unroll
    for (int mh = 0; mh < 2; ++mh) {
#pragma unroll
      for (int kk = 0; kk < 2; ++kk) {
        bf16x8 a[4];
#pragma unroll
        for (int mi = 0; mi < 4; ++mi)
          a[mi] = *(const bf16x8*)&As[cur][(wr * 128 + (mh * 4 + mi) * 16 + lr) * 64 +
                                          (((kk * 4 + lg) ^ (lr & 7)) << 3)];
#pragma unroll
        for (int mi = 0; mi < 4; ++mi)
#pragma unroll
          for (int ni = 0; ni < 4; ++ni)
            acc[mh * 4 + mi][ni] = __builtin_amdgcn_mfma_f32_16x16x32_bf16(
                a[mi], bb[ni][kk], acc[mh * 4 + mi][ni], 0, 0, 0);
      }
    }
    __builtin_amdgcn_s_setprio(0);
    asm volatile("s_waitcnt vmcnt(0)" ::: "memory");
    __builtin_amdgcn_s_barrier();
  }
#undef STGA
#undef STGB

  if (z < 2) {
    // rope epilogue: pairs (even,odd col) sit in adjacent lanes -> shfl_xor(1)
    ushort_t* outp = (z == 0) ? qb : kb;
    const float sc = (z == 0) ? 0.125f : 1.0f;
#pragma unroll
    for (int mi = 0; mi < 8; ++mi) {
      int rowb = m0 + wr * 128 + mi * 16 + lg * 4;
#pragma unroll
      for (int ni = 0; ni < 4; ++ni) {
        int col = n0 + wc * 64 + ni * 16 + lr;
        float bvv = bias[col];
        int ii = (col & 63) >> 1;
        int codd = col & 1;
#pragma unroll
        for (int r = 0; r < 4; ++r) {
          float val = acc[mi][ni][r] + bvv;
          float par = __shfl_xor(val, 1);
          float2 cs = csb[((rowb + r) & 511) * 32 + ii];
          float y = codd ? (par * cs.y + val * cs.x) : (val * cs.x - par * cs.y);
          outp[(size_t)(rowb + r) * 1024 + col] = f2bf(y * sc);
        }
      }
    }
  } else {
    // V: write transposed to vt[(b*1024 + col)][l], 4 consecutive l per lane -> b64
#pragma unroll
    for (int mi = 0; mi < 8; ++mi) {
      int rowb = m0 + wr * 128 + mi * 16 + lg * 4;
      int bidx = rowb >> 9, l0 = rowb & 511;
#pragma unroll
      for (int ni = 0; ni < 4; ++ni) {
        int col = n0 + wc * 64 + ni * 16 + lr;
        float bvv = bias[col];
        unsigned long long pk =
            (unsigned long long)f2bf(acc[mi][ni][0] + bvv)
          | ((unsigned long long)f2bf(acc[mi][ni][1] + bvv) << 16)
          | ((unsigned long long)f2bf(acc[mi][ni][2] + bvv) << 32)
          | ((unsigned long long)f2bf(acc[mi][ni][3] + bvv) << 48);
        *(unsigned long long*)&vt[((size_t)(bidx << 10) + col) * 512 + l0] = pk;
      }
    }
  }
}

// ---------------- O GEMM: 64x128 tile (512 blocks), BK=64, single-buffer; fp32 out ----------------
__global__ __launch_bounds__(256) void gemm_o_kernel(const ushort_t* __restrict__ A,
                                                     const ushort_t* __restrict__ Bt,
                                                     const float* __restrict__ bias,
                                                     const float* __restrict__ res,
                                                     float* __restrict__ out) {
  __shared__ ushort_t As[64 * 64];
  __shared__ ushort_t Bs[128 * 64];
  int t = threadIdx.x, l = t & 63, w = t >> 6, lr = l & 15, lg = l >> 4;
  int hid = blockIdx.x;
  int lid = (hid & 7) * 64 + (hid >> 3);
  int bx = lid & 7, by = lid >> 3;
  int m0 = by * 64, n0 = bx * 128;
  int wr = w >> 1, wc = w & 1;   // 2x2 waves: 32 rows x 64 cols each
  const int srow = l >> 3;
  const int scol = ((l & 7) ^ (srow & 7)) * 8;

  f32x4 acc[2][4] = {};

  for (int k0 = 0; k0 < 1024; k0 += 64) {
#pragma unroll
    for (int i = 0; i < 2; ++i)
      gl_lds16(&A[(size_t)(m0 + w * 16 + i * 8 + srow) * 1024 + k0 + scol],
               &As[(w * 16 + i * 8) * 64]);
#pragma unroll
    for (int i = 0; i < 4; ++i)
      gl_lds16(&Bt[(size_t)(n0 + w * 32 + i * 8 + srow) * 1024 + k0 + scol],
               &Bs[(w * 32 + i * 8) * 64]);
    __syncthreads();
#pragma unroll
    for (int kk = 0; kk < 2; ++kk) {
      bf16x8 a[2], bfr[4];
#pragma unroll
      for (int mi = 0; mi < 2; ++mi)
        a[mi] = *(const bf16x8*)&As[(wr * 32 + mi * 16 + lr) * 64 + (((kk * 4 + lg) ^ (lr & 7)) << 3)];
#pragma unroll
      for (int ni = 0; ni < 4; ++ni)
        bfr[ni] = *(const bf16x8*)&Bs[(wc * 64 + ni * 16 + lr) * 64 + (((kk * 4 + lg) ^ (lr & 7)) << 3)];
#pragma unroll
      for (int mi = 0; mi < 2; ++mi)
#pragma unroll
        for (int ni = 0; ni < 4; ++ni)
          acc[mi][ni] = __builtin_amdgcn_mfma_f32_16x16x32_bf16(a[mi], bfr[ni], acc[mi][ni], 0, 0, 0);
    }
    __syncthreads();
  }

#pragma unroll
  for (int mi = 0; mi < 2; ++mi) {
    int rowb = m0 + wr * 32 + mi * 16 + lg * 4;
#pragma unroll
    for (int ni = 0; ni < 4; ++ni) {
      int col = n0 + wc * 64 + ni * 16 + lr;
      float bvv = bias[col];
#pragma unroll
      for (int r = 0; r < 4; ++r) {
        size_t off = (size_t)(rowb + r) * 1024 + col;
        out[off] = acc[mi][ni][r] + bvv + res[off];
      }
    }
  }
}

// ---------------- Flash attention, swapped-operand form (round-5, verified) ----------------
__global__ __launch_bounds__(256) void attn_kernel(const ushort_t* __restrict__ q,
                                                   const ushort_t* __restrict__ k,
                                                   const ushort_t* __restrict__ vt,
                                                   ushort_t* __restrict__ o) {
  __shared__ ushort_t Ks[2][64 * 64];
  __shared__ ushort_t Vs[2][64 * 64];
  __shared__ ushort_t Ps[4][2][16 * 64];
  int t = threadIdx.x, l = t & 63, w = t >> 6, lr = l & 15, lg = l >> 4;
  int blk = blockIdx.x;
  int bh = blk & 127, qt = blk >> 7;
  int b = bh >> 4, h = bh & 15;
  const int srow = l >> 3;
  const int scol = ((l & 7) ^ (srow & 7)) * 8;

  bf16x8 qf[2][2];
#pragma unroll
  for (int qm = 0; qm < 2; ++qm) {
    size_t qrow = (size_t)(b * 512 + qt * 128 + w * 32 + qm * 16 + lr);
#pragma unroll
    for (int kh = 0; kh < 2; ++kh)
      qf[qm][kh] = *(const bf16x8*)&q[qrow * 1024 + h * 64 + kh * 32 + lg * 8];
  }

  f32x4 oacc[2][4] = {};
  float mrun[2] = {-1e30f, -1e30f};
  float lrun[2] = {0.f, 0.f};

#define STAGE(buf, kv0)                                                              \
  {                                                                                  \
    _Pragma("unroll")                                                                \
    for (int j = 0; j < 2; ++j) {                                                    \
      gl_lds16(&k[(size_t)(b * 512 + (kv0) + w * 16 + j * 8 + srow) * 1024 + h * 64 + scol], \
               &Ks[buf][(w * 16 + j * 8) * 64]);                                     \
      gl_lds16(&vt[((size_t)bh * 64 + w * 16 + j * 8 + srow) * 512 + (kv0) + scol],  \
               &Vs[buf][(w * 16 + j * 8) * 64]);                                     \
    }                                                                                \
  }

  STAGE(0, 0);
  __syncthreads();
  int cur = 0;
  for (int it = 0; it < 8; ++it) {
    if (it < 7) { STAGE(cur ^ 1, (it + 1) * 64); }
    bf16x8 kf[2][4];
#pragma unroll
    for (int kh = 0; kh < 2; ++kh)
#pragma unroll
      for (int kn = 0; kn < 4; ++kn)
        kf[kh][kn] = *(const bf16x8*)&Ks[cur][(kn * 16 + lr) * 64 + (((kh * 4 + lg) ^ (lr & 7)) << 3)];

#pragma unroll
    for (int qm = 0; qm < 2; ++qm) {
      f32x4 st[4] = {};
#pragma unroll
      for (int kh = 0; kh < 2; ++kh)
#pragma unroll
        for (int kn = 0; kn < 4; ++kn)
          st[kn] = __builtin_amdgcn_mfma_f32_16x16x32_bf16(kf[kh][kn], qf[qm][kh], st[kn], 0, 0, 0);
      float mx = st[0][0];
#pragma unroll
      for (int kn = 0; kn < 4; ++kn)
#pragma unroll
        for (int r = 0; r < 4; ++r) mx = fmaxf(mx, st[kn][r]);
      mx = fmaxf(mx, __shfl_xor(mx, 16));
      mx = fmaxf(mx, __shfl_xor(mx, 32));
      float mn = mrun[qm], al = 1.0f;
      if (!__all(mx <= mrun[qm] + 8.0f)) {
        mn = fmaxf(mrun[qm], mx);
        al = __expf(mrun[qm] - mn);
        mrun[qm] = mn;
#pragma unroll
        for (int f = 0; f < 4; ++f) {
          oacc[qm][f][0] *= al; oacc[qm][f][1] *= al;
          oacc[qm][f][2] *= al; oacc[qm][f][3] *= al;
        }
      }
      float sm = 0.f;
#pragma unroll
      for (int kn = 0; kn < 4; ++kn) {
        float p0 = __expf(st[kn][0] - mn);
        float p1 = __expf(st[kn][1] - mn);
        float p2 = __expf(st[kn][2] - mn);
        float p3 = __expf(st[kn][3] - mn);
        sm += p0 + p1 + p2 + p3;
        int kvb = kn * 16 + 4 * lg;
        unsigned long long pk =
            (unsigned long long)f2bf(p0)
          | ((unsigned long long)f2bf(p1) << 16)
          | ((unsigned long long)f2bf(p2) << 32)
          | ((unsigned long long)f2bf(p3) << 48);
        *(unsigned long long*)&Ps[w][qm][lr * 64 + (((kvb >> 3) ^ (lr & 7)) << 3) + (kvb & 7)] = pk;
      }
      sm += __shfl_xor(sm, 16);
      sm += __shfl_xor(sm, 32);
      lrun[qm] = lrun[qm] * al + sm;
    }
    asm volatile("s_waitcnt lgkmcnt(0)" ::: "memory");
    __builtin_amdgcn_sched_barrier(0);
#pragma unroll
    for (int kk = 0; kk < 2; ++kk) {
      int sl = (((kk * 4 + lg) ^ (lr & 7)) << 3);
      bf16x8 pb[2];
#pragma unroll
      for (int qm = 0; qm < 2; ++qm)
        pb[qm] = *(const bf16x8*)&Ps[w][qm][lr * 64 + sl];
#pragma unroll
      for (int f = 0; f < 4; ++f) {
        bf16x8 vf = *(const bf16x8*)&Vs[cur][(f * 16 + lr) * 64 + sl];
#pragma unroll
        for (int qm = 0; qm < 2; ++qm)
          oacc[qm][f] = __builtin_amdgcn_mfma_f32_16x16x32_bf16(vf, pb[qm], oacc[qm][f], 0, 0, 0);
      }
    }
    __syncthreads();
    cur ^= 1;
  }
#pragma unroll
  for (int qm = 0; qm < 2; ++qm) {
    float inv = 1.0f / lrun[qm];
    size_t qrow = (size_t)(b * 512 + qt * 128 + w * 32 + qm * 16 + lr);
#pragma unroll
    for (int f = 0; f < 4; ++f) {
      unsigned long long pk =
          (unsigned long long)f2bf(oacc[qm][f][0] * inv)
        | ((unsigned long long)f2bf(oacc[qm][f][1] * inv) << 16)
        | ((unsigned long long)f2bf(oacc[qm][f][2] * inv) << 32)
        | ((unsigned long long)f2bf(oacc[qm][f][3] * inv) << 48);
      *(unsigned long long*)&o[qrow * 1024 + h * 64 + f * 16 + 4 * lg] = pk;
    }
  }
#undef STAGE
}

// ---------------- launch ----------------
extern "C" void kernel_launch(void* const* d_in, const int* in_sizes, int n_in,
                              void* d_out, int out_size, void* d_ws, size_t ws_size,
                              hipStream_t stream) {
  const float* input_ids = (const float*)d_in[0];
  const float* Wq = (const float*)d_in[1];
  const float* bq = (const float*)d_in[2];
  const float* Wk = (const float*)d_in[3];
  const float* bk = (const float*)d_in[4];
  const float* Wv = (const float*)d_in[5];
  const float* bv = (const float*)d_in[6];
  const float* Wo = (const float*)d_in[7];
  const float* bo = (const float*)d_in[8];
  const float* g_attn = (const float*)d_in[13];
  const float* b_attn = (const float*)d_in[14];
  float* out = (float*)d_out;

  char* ws = (char*)d_ws;
  const size_t MB = 1024 * 1024;
  ushort_t* wt = (ushort_t*)(ws);             // 8MB: Wq^T,Wk^T,Wv^T,Wo^T bf16 (contiguous)
  ushort_t* xn = (ushort_t*)(ws + 8 * MB);    // 8MB: LN out, later attn O
  ushort_t* qb = (ushort_t*)(ws + 16 * MB);   // 8MB
  ushort_t* kb = (ushort_t*)(ws + 24 * MB);   // 8MB
  ushort_t* vt = (ushort_t*)(ws + 32 * MB);   // 8MB: V transposed [b*1024+col][l]
  float2* csb  = (float2*)(ws + 40 * MB);     // 128KB interleaved cos/sin

  prep_kernel<<<8256, 256, 0, stream>>>(input_ids, g_attn, b_attn, xn, csb,
                                        Wq, Wk, Wv, Wo, wt);
  gemm_qkv_kernel<<<192, 512, 0, stream>>>(xn, wt, bq, bk, bv, qb, kb, vt, csb);
  attn_kernel<<<512, 256, 0, stream>>>(qb, kb, vt, xn);  // xn <- O (bf16)
  gemm_o_kernel<<<512, 256, 0, stream>>>(xn, wt + 3 * MB, bo, input_ids, out);
}

// Round 9
// 90.112 us; speedup vs baseline: 1.2484x; 1.0763x over previous
//
#include <hip/hip_runtime.h>

typedef unsigned short ushort_t;
typedef short bf16x8 __attribute__((ext_vector_type(8)));
typedef float f32x4 __attribute__((ext_vector_type(4)));

#define B_ 8
#define L_ 512
#define D_ 1024
#define H_ 16
#define M_ 4096

__device__ __forceinline__ ushort_t f2bf(float f) {
  union { float f; unsigned u; } v; v.f = f;
  unsigned r = v.u + 0x7FFFu + ((v.u >> 16) & 1u);
  return (ushort_t)(r >> 16);
}

// global -> LDS direct (16B per lane, dest = wave-uniform base + lane*16)
__device__ __forceinline__ void gl_lds16(const ushort_t* g, ushort_t* s) {
  __builtin_amdgcn_global_load_lds((const __attribute__((address_space(1))) void*)(g),
                                   (__attribute__((address_space(3))) void*)(s), 16, 0, 0);
}

// ---------------- fused preamble: LN (blocks 0..4095), cos/sin table (4096..4159),
// ---------------- weight transpose+bf16 (4160..8255) ----------------
__global__ __launch_bounds__(256) void prep_kernel(const float* __restrict__ x,
                                                   const float* __restrict__ g,
                                                   const float* __restrict__ b,
                                                   ushort_t* __restrict__ xn,
                                                   float2* __restrict__ csb,
                                                   const float* __restrict__ w0,
                                                   const float* __restrict__ w1,
                                                   const float* __restrict__ w2,
                                                   const float* __restrict__ w3,
                                                   ushort_t* __restrict__ wt) {
  __shared__ float red[8];
  __shared__ float tile[32][33];
  int blk = blockIdx.x, t = threadIdx.x;
  if (blk < 4096) {
    int row = blk;
    float4 v = ((const float4*)(x + (size_t)row * D_))[t];
    float s  = v.x + v.y + v.z + v.w;
    float s2 = v.x * v.x + v.y * v.y + v.z * v.z + v.w * v.w;
#pragma unroll
    for (int m = 1; m < 64; m <<= 1) { s += __shfl_xor(s, m); s2 += __shfl_xor(s2, m); }
    int w = t >> 6;
    if ((t & 63) == 0) { red[w] = s; red[4 + w] = s2; }
    __syncthreads();
    s  = red[0] + red[1] + red[2] + red[3];
    s2 = red[4] + red[5] + red[6] + red[7];
    float mean = s * (1.0f / D_);
    float var  = s2 * (1.0f / D_) - mean * mean;
    float rs   = rsqrtf(var + 1e-5f);
    float4 gg = ((const float4*)g)[t];
    float4 bb = ((const float4*)b)[t];
    unsigned long long pk =
        (unsigned long long)f2bf((v.x - mean) * rs * gg.x + bb.x)
      | ((unsigned long long)f2bf((v.y - mean) * rs * gg.y + bb.y) << 16)
      | ((unsigned long long)f2bf((v.z - mean) * rs * gg.z + bb.z) << 32)
      | ((unsigned long long)f2bf((v.w - mean) * rs * gg.w + bb.w) << 48);
    *(unsigned long long*)(xn + (size_t)row * D_ + t * 4) = pk;
  } else if (blk < 4160) {
    int idx = (blk - 4096) * 256 + t;
    int l = idx >> 5, i = idx & 31;
    float inv = powf(10000.0f, (-2.0f * (float)i) / 1024.0f);
    float ang = (float)l * inv;
    csb[idx] = make_float2(cosf(ang), sinf(ang));
  } else {
    int wb = blk - 4160;
    int z = wb >> 10;
    const float* W = (z == 0) ? w0 : (z == 1) ? w1 : (z == 2) ? w2 : w3;
    ushort_t* WT = wt + ((size_t)z << 20);
    int rem = wb & 1023;
    int by = rem >> 5, bx = rem & 31;
    int tx = t & 31, ty = t >> 5;  // 32 x 8
    int k0 = by * 32, n0 = bx * 32;
#pragma unroll
    for (int j = 0; j < 4; ++j)
      tile[ty + 8 * j][tx] = W[(size_t)(k0 + ty + 8 * j) * 1024 + n0 + tx];
    __syncthreads();
#pragma unroll
    for (int j = 0; j < 4; ++j)
      WT[(size_t)(n0 + ty + 8 * j) * 1024 + k0 + tx] = f2bf(tile[tx][ty + 8 * j]);
  }
}

// ---------------- Fused QKV GEMM: 64x128 tile, BK=64, 4 waves, 24KB LDS ----------------
// Grid 1536 blocks -> 6 resident blocks/CU (24 waves) for cross-block stall hiding.
// 2D XCD map: XCD x owns by in [ (x>>1)*16, +16 ) x bx in [ (x&1)*12, +12 ).
// Epilogue by n-range: q=rope*0.125 ; k=rope ; v -> transposed vt
__global__ __launch_bounds__(256) void gemm_qkv_kernel(const ushort_t* __restrict__ xn,
                                                       const ushort_t* __restrict__ wt,
                                                       const float* __restrict__ bq,
                                                       const float* __restrict__ bk,
                                                       const float* __restrict__ bv,
                                                       ushort_t* __restrict__ qb,
                                                       ushort_t* __restrict__ kb,
                                                       ushort_t* __restrict__ vt,
                                                       const float2* __restrict__ csb) {
  __shared__ ushort_t As[64 * 64];    // 8 KB
  __shared__ ushort_t Bs[128 * 64];   // 16 KB
  int t = threadIdx.x, l = t & 63, w = t >> 6, lr = l & 15, lg = l >> 4;
  int hid = blockIdx.x;
  int xcd = hid & 7, lid = hid >> 3;           // lid 0..191
  int by = (xcd >> 1) * 16 + lid / 12;         // 0..63
  int bx = (xcd & 1) * 12 + lid % 12;          // 0..23
  int m0 = by * 64;
  int n0g = bx * 128;
  int z = n0g >> 10;
  int n0 = n0g & 1023;
  const float* bias = (z == 0) ? bq : (z == 1) ? bk : bv;
  int wr = w >> 1, wc = w & 1;                 // per-wave 32 rows x 64 cols
  const int sr8 = l >> 3;
  const int scol = ((l & 7) ^ sr8) * 8;        // pre-swizzled source col

  f32x4 acc[2][4] = {};

  for (int k0 = 0; k0 < 1024; k0 += 64) {
    // A: 8 chunks of 8 rows, wave w stages rows [w*16, w*16+16)
    gl_lds16(&xn[(size_t)(m0 + w * 16 + sr8) * 1024 + k0 + scol], &As[(w * 16) * 64]);
    gl_lds16(&xn[(size_t)(m0 + w * 16 + 8 + sr8) * 1024 + k0 + scol], &As[(w * 16 + 8) * 64]);
    // B: 16 chunks, wave w stages rows [w*32, w*32+32)
    gl_lds16(&wt[(size_t)(n0g + w * 32 + sr8) * 1024 + k0 + scol], &Bs[(w * 32) * 64]);
    gl_lds16(&wt[(size_t)(n0g + w * 32 + 8 + sr8) * 1024 + k0 + scol], &Bs[(w * 32 + 8) * 64]);
    gl_lds16(&wt[(size_t)(n0g + w * 32 + 16 + sr8) * 1024 + k0 + scol], &Bs[(w * 32 + 16) * 64]);
    gl_lds16(&wt[(size_t)(n0g + w * 32 + 24 + sr8) * 1024 + k0 + scol], &Bs[(w * 32 + 24) * 64]);
    __syncthreads();
#pragma unroll
    for (int kk = 0; kk < 2; ++kk) {
      bf16x8 a[2], bfr[4];
#pragma unroll
      for (int mi = 0; mi < 2; ++mi)
        a[mi] = *(const bf16x8*)&As[(wr * 32 + mi * 16 + lr) * 64 + (((kk * 4 + lg) ^ (lr & 7)) << 3)];
#pragma unroll
      for (int ni = 0; ni < 4; ++ni)
        bfr[ni] = *(const bf16x8*)&Bs[(wc * 64 + ni * 16 + lr) * 64 + (((kk * 4 + lg) ^ (lr & 7)) << 3)];
#pragma unroll
      for (int mi = 0; mi < 2; ++mi)
#pragma unroll
        for (int ni = 0; ni < 4; ++ni)
          acc[mi][ni] = __builtin_amdgcn_mfma_f32_16x16x32_bf16(a[mi], bfr[ni], acc[mi][ni], 0, 0, 0);
    }
    __syncthreads();
  }

  if (z < 2) {
    // rope epilogue: pairs (even,odd col) sit in adjacent lanes -> shfl_xor(1)
    ushort_t* outp = (z == 0) ? qb : kb;
    const float sc = (z == 0) ? 0.125f : 1.0f;
#pragma unroll
    for (int mi = 0; mi < 2; ++mi) {
      int rowb = m0 + wr * 32 + mi * 16 + lg * 4;
#pragma unroll
      for (int ni = 0; ni < 4; ++ni) {
        int col = n0 + wc * 64 + ni * 16 + lr;
        float bvv = bias[col];
        int ii = (col & 63) >> 1;
        int codd = col & 1;
#pragma unroll
        for (int r = 0; r < 4; ++r) {
          float val = acc[mi][ni][r] + bvv;
          float par = __shfl_xor(val, 1);
          float2 cs = csb[((rowb + r) & 511) * 32 + ii];
          float y = codd ? (par * cs.y + val * cs.x) : (val * cs.x - par * cs.y);
          outp[(size_t)(rowb + r) * 1024 + col] = f2bf(y * sc);
        }
      }
    }
  } else {
    // V: write transposed to vt[(b*1024 + col)][l], 4 consecutive l per lane -> b64
#pragma unroll
    for (int mi = 0; mi < 2; ++mi) {
      int rowb = m0 + wr * 32 + mi * 16 + lg * 4;
      int bidx = rowb >> 9, l0 = rowb & 511;
#pragma unroll
      for (int ni = 0; ni < 4; ++ni) {
        int col = n0 + wc * 64 + ni * 16 + lr;
        float bvv = bias[col];
        unsigned long long pk =
            (unsigned long long)f2bf(acc[mi][ni][0] + bvv)
          | ((unsigned long long)f2bf(acc[mi][ni][1] + bvv) << 16)
          | ((unsigned long long)f2bf(acc[mi][ni][2] + bvv) << 32)
          | ((unsigned long long)f2bf(acc[mi][ni][3] + bvv) << 48);
        *(unsigned long long*)&vt[((size_t)(bidx << 10) + col) * 512 + l0] = pk;
      }
    }
  }
}

// ---------------- O GEMM: 64x128 tile (512 blocks), BK=64, single-buffer; fp32 out ----------------
__global__ __launch_bounds__(256) void gemm_o_kernel(const ushort_t* __restrict__ A,
                                                     const ushort_t* __restrict__ Bt,
                                                     const float* __restrict__ bias,
                                                     const float* __restrict__ res,
                                                     float* __restrict__ out) {
  __shared__ ushort_t As[64 * 64];
  __shared__ ushort_t Bs[128 * 64];
  int t = threadIdx.x, l = t & 63, w = t >> 6, lr = l & 15, lg = l >> 4;
  int hid = blockIdx.x;
  int lid = (hid & 7) * 64 + (hid >> 3);
  int bx = lid & 7, by = lid >> 3;
  int m0 = by * 64, n0 = bx * 128;
  int wr = w >> 1, wc = w & 1;   // 2x2 waves: 32 rows x 64 cols each
  const int srow = l >> 3;
  const int scol = ((l & 7) ^ (srow & 7)) * 8;

  f32x4 acc[2][4] = {};

  for (int k0 = 0; k0 < 1024; k0 += 64) {
#pragma unroll
    for (int i = 0; i < 2; ++i)
      gl_lds16(&A[(size_t)(m0 + w * 16 + i * 8 + srow) * 1024 + k0 + scol],
               &As[(w * 16 + i * 8) * 64]);
#pragma unroll
    for (int i = 0; i < 4; ++i)
      gl_lds16(&Bt[(size_t)(n0 + w * 32 + i * 8 + srow) * 1024 + k0 + scol],
               &Bs[(w * 32 + i * 8) * 64]);
    __syncthreads();
#pragma unroll
    for (int kk = 0; kk < 2; ++kk) {
      bf16x8 a[2], bfr[4];
#pragma unroll
      for (int mi = 0; mi < 2; ++mi)
        a[mi] = *(const bf16x8*)&As[(wr * 32 + mi * 16 + lr) * 64 + (((kk * 4 + lg) ^ (lr & 7)) << 3)];
#pragma unroll
      for (int ni = 0; ni < 4; ++ni)
        bfr[ni] = *(const bf16x8*)&Bs[(wc * 64 + ni * 16 + lr) * 64 + (((kk * 4 + lg) ^ (lr & 7)) << 3)];
#pragma unroll
      for (int mi = 0; mi < 2; ++mi)
#pragma unroll
        for (int ni = 0; ni < 4; ++ni)
          acc[mi][ni] = __builtin_amdgcn_mfma_f32_16x16x32_bf16(a[mi], bfr[ni], acc[mi][ni], 0, 0, 0);
    }
    __syncthreads();
  }

#pragma unroll
  for (int mi = 0; mi < 2; ++mi) {
    int rowb = m0 + wr * 32 + mi * 16 + lg * 4;
#pragma unroll
    for (int ni = 0; ni < 4; ++ni) {
      int col = n0 + wc * 64 + ni * 16 + lr;
      float bvv = bias[col];
#pragma unroll
      for (int r = 0; r < 4; ++r) {
        size_t off = (size_t)(rowb + r) * 1024 + col;
        out[off] = acc[mi][ni][r] + bvv + res[off];
      }
    }
  }
}

// ---------------- Flash attention, swapped-operand form (round-5, verified) ----------------
__global__ __launch_bounds__(256) void attn_kernel(const ushort_t* __restrict__ q,
                                                   const ushort_t* __restrict__ k,
                                                   const ushort_t* __restrict__ vt,
                                                   ushort_t* __restrict__ o) {
  __shared__ ushort_t Ks[2][64 * 64];
  __shared__ ushort_t Vs[2][64 * 64];
  __shared__ ushort_t Ps[4][2][16 * 64];
  int t = threadIdx.x, l = t & 63, w = t >> 6, lr = l & 15, lg = l >> 4;
  int blk = blockIdx.x;
  int bh = blk & 127, qt = blk >> 7;
  int b = bh >> 4, h = bh & 15;
  const int srow = l >> 3;
  const int scol = ((l & 7) ^ (srow & 7)) * 8;

  bf16x8 qf[2][2];
#pragma unroll
  for (int qm = 0; qm < 2; ++qm) {
    size_t qrow = (size_t)(b * 512 + qt * 128 + w * 32 + qm * 16 + lr);
#pragma unroll
    for (int kh = 0; kh < 2; ++kh)
      qf[qm][kh] = *(const bf16x8*)&q[qrow * 1024 + h * 64 + kh * 32 + lg * 8];
  }

  f32x4 oacc[2][4] = {};
  float mrun[2] = {-1e30f, -1e30f};
  float lrun[2] = {0.f, 0.f};

#define STAGE(buf, kv0)                                                              \
  {                                                                                  \
    _Pragma("unroll")                                                                \
    for (int j = 0; j < 2; ++j) {                                                    \
      gl_lds16(&k[(size_t)(b * 512 + (kv0) + w * 16 + j * 8 + srow) * 1024 + h * 64 + scol], \
               &Ks[buf][(w * 16 + j * 8) * 64]);                                     \
      gl_lds16(&vt[((size_t)bh * 64 + w * 16 + j * 8 + srow) * 512 + (kv0) + scol],  \
               &Vs[buf][(w * 16 + j * 8) * 64]);                                     \
    }                                                                                \
  }

  STAGE(0, 0);
  __syncthreads();
  int cur = 0;
  for (int it = 0; it < 8; ++it) {
    if (it < 7) { STAGE(cur ^ 1, (it + 1) * 64); }
    bf16x8 kf[2][4];
#pragma unroll
    for (int kh = 0; kh < 2; ++kh)
#pragma unroll
      for (int kn = 0; kn < 4; ++kn)
        kf[kh][kn] = *(const bf16x8*)&Ks[cur][(kn * 16 + lr) * 64 + (((kh * 4 + lg) ^ (lr & 7)) << 3)];

#pragma unroll
    for (int qm = 0; qm < 2; ++qm) {
      f32x4 st[4] = {};
#pragma unroll
      for (int kh = 0; kh < 2; ++kh)
#pragma unroll
        for (int kn = 0; kn < 4; ++kn)
          st[kn] = __builtin_amdgcn_mfma_f32_16x16x32_bf16(kf[kh][kn], qf[qm][kh], st[kn], 0, 0, 0);
      float mx = st[0][0];
#pragma unroll
      for (int kn = 0; kn < 4; ++kn)
#pragma unroll
        for (int r = 0; r < 4; ++r) mx = fmaxf(mx, st[kn][r]);
      mx = fmaxf(mx, __shfl_xor(mx, 16));
      mx = fmaxf(mx, __shfl_xor(mx, 32));
      float mn = mrun[qm], al = 1.0f;
      if (!__all(mx <= mrun[qm] + 8.0f)) {
        mn = fmaxf(mrun[qm], mx);
        al = __expf(mrun[qm] - mn);
        mrun[qm] = mn;
#pragma unroll
        for (int f = 0; f < 4; ++f) {
          oacc[qm][f][0] *= al; oacc[qm][f][1] *= al;
          oacc[qm][f][2] *= al; oacc[qm][f][3] *= al;
        }
      }
      float sm = 0.f;
#pragma unroll
      for (int kn = 0; kn < 4; ++kn) {
        float p0 = __expf(st[kn][0] - mn);
        float p1 = __expf(st[kn][1] - mn);
        float p2 = __expf(st[kn][2] - mn);
        float p3 = __expf(st[kn][3] - mn);
        sm += p0 + p1 + p2 + p3;
        int kvb = kn * 16 + 4 * lg;
        unsigned long long pk =
            (unsigned long long)f2bf(p0)
          | ((unsigned long long)f2bf(p1) << 16)
          | ((unsigned long long)f2bf(p2) << 32)
          | ((unsigned long long)f2bf(p3) << 48);
        *(unsigned long long*)&Ps[w][qm][lr * 64 + (((kvb >> 3) ^ (lr & 7)) << 3) + (kvb & 7)] = pk;
      }
      sm += __shfl_xor(sm, 16);
      sm += __shfl_xor(sm, 32);
      lrun[qm] = lrun[qm] * al + sm;
    }
    asm volatile("s_waitcnt lgkmcnt(0)" ::: "memory");
    __builtin_amdgcn_sched_barrier(0);
#pragma unroll
    for (int kk = 0; kk < 2; ++kk) {
      int sl = (((kk * 4 + lg) ^ (lr & 7)) << 3);
      bf16x8 pb[2];
#pragma unroll
      for (int qm = 0; qm < 2; ++qm)
        pb[qm] = *(const bf16x8*)&Ps[w][qm][lr * 64 + sl];
#pragma unroll
      for (int f = 0; f < 4; ++f) {
        bf16x8 vf = *(const bf16x8*)&Vs[cur][(f * 16 + lr) * 64 + sl];
#pragma unroll
        for (int qm = 0; qm < 2; ++qm)
          oacc[qm][f] = __builtin_amdgcn_mfma_f32_16x16x32_bf16(vf, pb[qm], oacc[qm][f], 0, 0, 0);
      }
    }
    __syncthreads();
    cur ^= 1;
  }
#pragma unroll
  for (int qm = 0; qm < 2; ++qm) {
    float inv = 1.0f / lrun[qm];
    size_t qrow = (size_t)(b * 512 + qt * 128 + w * 32 + qm * 16 + lr);
#pragma unroll
    for (int f = 0; f < 4; ++f) {
      unsigned long long pk =
          (unsigned long long)f2bf(oacc[qm][f][0] * inv)
        | ((unsigned long long)f2bf(oacc[qm][f][1] * inv) << 16)
        | ((unsigned long long)f2bf(oacc[qm][f][2] * inv) << 32)
        | ((unsigned long long)f2bf(oacc[qm][f][3] * inv) << 48);
      *(unsigned long long*)&o[qrow * 1024 + h * 64 + f * 16 + 4 * lg] = pk;
    }
  }
#undef STAGE
}

// ---------------- launch ----------------
extern "C" void kernel_launch(void* const* d_in, const int* in_sizes, int n_in,
                              void* d_out, int out_size, void* d_ws, size_t ws_size,
                              hipStream_t stream) {
  const float* input_ids = (const float*)d_in[0];
  const float* Wq = (const float*)d_in[1];
  const float* bq = (const float*)d_in[2];
  const float* Wk = (const float*)d_in[3];
  const float* bk = (const float*)d_in[4];
  const float* Wv = (const float*)d_in[5];
  const float* bv = (const float*)d_in[6];
  const float* Wo = (const float*)d_in[7];
  const float* bo = (const float*)d_in[8];
  const float* g_attn = (const float*)d_in[13];
  const float* b_attn = (const float*)d_in[14];
  float* out = (float*)d_out;

  char* ws = (char*)d_ws;
  const size_t MB = 1024 * 1024;
  ushort_t* wt = (ushort_t*)(ws);             // 8MB: Wq^T,Wk^T,Wv^T,Wo^T bf16 (contiguous)
  ushort_t* xn = (ushort_t*)(ws + 8 * MB);    // 8MB: LN out, later attn O
  ushort_t* qb = (ushort_t*)(ws + 16 * MB);   // 8MB
  ushort_t* kb = (ushort_t*)(ws + 24 * MB);   // 8MB
  ushort_t* vt = (ushort_t*)(ws + 32 * MB);   // 8MB: V transposed [b*1024+col][l]
  float2* csb  = (float2*)(ws + 40 * MB);     // 128KB interleaved cos/sin

  prep_kernel<<<8256, 256, 0, stream>>>(input_ids, g_attn, b_attn, xn, csb,
                                        Wq, Wk, Wv, Wo, wt);
  gemm_qkv_kernel<<<1536, 256, 0, stream>>>(xn, wt, bq, bk, bv, qb, kb, vt, csb);
  attn_kernel<<<512, 256, 0, stream>>>(qb, kb, vt, xn);  // xn <- O (bf16)
  gemm_o_kernel<<<512, 256, 0, stream>>>(xn, wt + 3 * MB, bo, input_ids, out);
}